// Round 10
// baseline (211.895 us; speedup 1.0000x reference)
//
#include <hip/hip_runtime.h>
#include <hip/hip_bf16.h>
#include <stdint.h>

#define B_ROWS 2048
#define SEQ 512
#define VOC 30000
#define DMODEL 768
#define K1 1.2f
#define BPAR 0.75f
#define NT 192   // 3 waves; each thread owns one ushort4 (4 bf16) chunk of 768 dims
#define PF 16    // prefetch depth (outstanding global loads per thread)

// ---------------- Kernel 1: transpose W [768][30000] f32 -> Wb [30000][768] bf16 -------
// 64x64 tile, block (64,4). Reads: 256B/wave segments. Writes: full 128B lines.
__launch_bounds__(256)
__global__ void transpose_W64(const float* __restrict__ W, __hip_bfloat16* __restrict__ Wb) {
    __shared__ __hip_bfloat16 tile[64][66];  // [j_local][t_local]; 66 -> conflict-free cols
    int tBase = blockIdx.x * 64;
    int jBase = blockIdx.y * 64;
    int tx = threadIdx.x;   // 0..63
    int ty = threadIdx.y;   // 0..3

#pragma unroll
    for (int jj = 0; jj < 16; jj++) {
        int j = jBase + jj * 4 + ty;
        int t = tBase + tx;
        float v = (t < VOC) ? W[(size_t)j * VOC + t] : 0.f;
        tile[jj * 4 + ty][tx] = __float2bfloat16(v);
    }
    __syncthreads();

#pragma unroll
    for (int tt = 0; tt < 16; tt++) {
        int t = tBase + tt * 4 + ty;
        if (t < VOC) {
            Wb[(size_t)t * DMODEL + jBase + tx] = tile[tx][tt * 4 + ty];
        }
    }
}

__device__ __forceinline__ float b2f(unsigned short h) {
    union { uint32_t u; float f; } v; v.u = ((uint32_t)h) << 16; return v.f;
}

// ---------------- Kernel 2: per-row BM25 sparse accumulate + normalize ----------------
// R7's proven structure; single knob changed: PF 8 -> 16 (more outstanding loads to cut
// the ~50% load-stall). The 1e-10*ones@W^T term is dropped (R4/R6 evidence: identical
// absmax without it; ~1e-10 relative); rsqrtf guard covers the n==0 case.
__launch_bounds__(NT, 6)
__global__ void bm25_main(const int* __restrict__ ids, const int* __restrict__ mask,
                          const __hip_bfloat16* __restrict__ Wb,
                          float* __restrict__ out) {
    __shared__ int   stoks[SEQ];
    __shared__ float wts[SEQ];
    __shared__ int   nv;
    __shared__ float wred[3];

    int b = blockIdx.x;
    int tid = threadIdx.x;

    if (tid == 0) nv = 0;
    __syncthreads();

    // compact valid tokens (order irrelevant; sort follows)
    for (int i = tid; i < SEQ; i += NT) {
        int id = ids[(size_t)b * SEQ + i];
        int m  = mask[(size_t)b * SEQ + i];
        if (m == 1 && id > 100 && id < VOC) {
            stoks[atomicAdd(&nv, 1)] = id;
        }
    }
    __syncthreads();
    int n = nv;  // == doc_len (positions with multiplicity)

    // pad to 512 with +inf keys
    for (int i = n + tid; i < SEQ; i += NT) stoks[i] = 0x7fffffff;

    // bitonic sort of 512 ints (first barrier inside loop covers padding writes)
    for (int k = 2; k <= SEQ; k <<= 1) {
        for (int j = k >> 1; j > 0; j >>= 1) {
            __syncthreads();
            for (int i = tid; i < SEQ; i += NT) {
                int ixj = i ^ j;
                if (ixj > i) {
                    int a = stoks[i], c = stoks[ixj];
                    if ((a > c) == ((i & k) == 0)) { stoks[i] = c; stoks[ixj] = a; }
                }
            }
        }
    }
    __syncthreads();

    // per-position weight: score(tf)/tf = (K1+1)/(tf + K1*len_norm); tf via sorted runs
    float kln = K1 * fmaxf(1.0f + BPAR * ((float)n / 100.0f - 1.0f), 0.5f);
    for (int i = tid; i < n; i += NT) {
        int t = stoks[i];
        int lo = i; while (lo > 0 && stoks[lo - 1] == t) lo--;
        int hi = i; while (hi < n - 1 && stoks[hi + 1] == t) hi++;
        wts[i] = (K1 + 1.0f) / ((float)(hi - lo + 1) + kln);
    }
    __syncthreads();

    // gather-accumulate in ascending vocab order; thread owns bf16x4 chunk `tid`
    const ushort4* __restrict__ Wb4 = (const ushort4*)Wb;   // row stride DMODEL/4 = 192
    float4 acc = make_float4(0.f, 0.f, 0.f, 0.f);
    int p = 0;
    for (; p + PF <= n; p += PF) {
        ushort4 r[PF];
        float   w[PF];
#pragma unroll
        for (int q = 0; q < PF; q++) {
            r[q] = Wb4[(size_t)stoks[p + q] * (DMODEL / 4) + tid];
            w[q] = wts[p + q];
        }
#pragma unroll
        for (int q = 0; q < PF; q++) {
            acc.x = fmaf(w[q], b2f(r[q].x), acc.x);
            acc.y = fmaf(w[q], b2f(r[q].y), acc.y);
            acc.z = fmaf(w[q], b2f(r[q].z), acc.z);
            acc.w = fmaf(w[q], b2f(r[q].w), acc.w);
        }
    }
    for (; p < n; p++) {
        float w = wts[p];
        ushort4 r = Wb4[(size_t)stoks[p] * (DMODEL / 4) + tid];
        acc.x = fmaf(w, b2f(r.x), acc.x);
        acc.y = fmaf(w, b2f(r.y), acc.y);
        acc.z = fmaf(w, b2f(r.z), acc.z);
        acc.w = fmaf(w, b2f(r.w), acc.w);
    }

    // L2 norm over 768 dims (intermediate normalize cancels; 1e-10 term ~1e-10 rel)
    float ss = acc.x * acc.x + acc.y * acc.y + acc.z * acc.z + acc.w * acc.w;
#pragma unroll
    for (int off = 32; off > 0; off >>= 1) ss += __shfl_down(ss, off);
    if ((tid & 63) == 0) wred[tid >> 6] = ss;
    __syncthreads();
    float inv = rsqrtf(fmaxf(wred[0] + wred[1] + wred[2], 1e-30f));

    float4 o;
    o.x = acc.x * inv; o.y = acc.y * inv; o.z = acc.z * inv; o.w = acc.w * inv;
    ((float4*)(out + (size_t)b * DMODEL))[tid] = o;
}

extern "C" void kernel_launch(void* const* d_in, const int* in_sizes, int n_in,
                              void* d_out, int out_size, void* d_ws, size_t ws_size,
                              hipStream_t stream) {
    const int*   ids  = (const int*)d_in[0];
    const int*   mask = (const int*)d_in[1];
    const float* W    = (const float*)d_in[2];
    float* out = (float*)d_out;

    __hip_bfloat16* Wb = (__hip_bfloat16*)d_ws;            // 30000*768*2 = 46,080,000 B

    dim3 tgrid((VOC + 63) / 64, DMODEL / 64);
    dim3 tblock(64, 4);
    transpose_W64<<<tgrid, tblock, 0, stream>>>(W, Wb);

    bm25_main<<<B_ROWS, NT, 0, stream>>>(ids, mask, Wb, out);
}

// Round 11
// 152.927 us; speedup vs baseline: 1.3856x; 1.3856x over previous
//
#include <hip/hip_runtime.h>
#include <hip/hip_bf16.h>
#include <stdint.h>

#define B_ROWS 2048
#define SEQ 512
#define VOC 30000
#define DMODEL 768
#define K1 1.2f
#define BPAR 0.75f
#define NT 192   // 3 waves; each thread owns one ushort4 (4 bf16) chunk of 768 dims
#define PF 8     // prefetch depth (outstanding global loads per thread) — R7-proven

// ---------------- Kernel 1: transpose W [768][30000] f32 -> Wb [30000][768] bf16 -------
// v2: 64j x 256t tiles. Reads: float4 (1KB/wave-instr). Writes: full 128B lines.
// LDS row stride 258 (odd dword stride 129) -> conflict-free column reads.
__launch_bounds__(256)
__global__ void transpose_W256(const float* __restrict__ W, __hip_bfloat16* __restrict__ Wb) {
    __shared__ __hip_bfloat16 tile[64][258];
    int tBase = blockIdx.x * 256;
    int jBase = blockIdx.y * 64;
    int tx = threadIdx.x;   // 0..63
    int ty = threadIdx.y;   // 0..3

    // read phase: wave ty reads j-rows jBase + jj*4 + ty; lane tx reads float4 at t
    // (VOC % 4 == 0, so t < VOC implies the full float4 is in range)
#pragma unroll
    for (int jj = 0; jj < 16; jj++) {
        int j = jBase + jj * 4 + ty;
        int t = tBase + tx * 4;
        if (t < VOC) {
            float4 v = *(const float4*)(W + (size_t)j * VOC + t);
            int c = tx * 4;
            tile[jj * 4 + ty][c]     = __float2bfloat16(v.x);
            tile[jj * 4 + ty][c + 1] = __float2bfloat16(v.y);
            tile[jj * 4 + ty][c + 2] = __float2bfloat16(v.z);
            tile[jj * 4 + ty][c + 3] = __float2bfloat16(v.w);
        }
    }
    __syncthreads();

    // write phase: wave ty writes t-rows i*4 + ty; 64 lanes x 2B = one full 128B line
#pragma unroll
    for (int i = 0; i < 64; i++) {
        int trow = i * 4 + ty;
        int t = tBase + trow;
        if (t < VOC) {
            Wb[(size_t)t * DMODEL + jBase + tx] = tile[tx][trow];
        }
    }
}

__device__ __forceinline__ float b2f(unsigned short h) {
    union { uint32_t u; float f; } v; v.u = ((uint32_t)h) << 16; return v.f;
}

// ---------------- Kernel 2: per-row BM25 sparse accumulate + normalize ----------------
// Gather loop BYTE-IDENTICAL to R7 (proven 4x: 128-129 us, FETCH at the 8x46MB floor).
// Only epilogue changed: 1e-10*colsum term dropped (R4/R6: identical absmax without it;
// term is ~1e-10 relative), rsqrtf guard covers n == 0.
__launch_bounds__(NT, 6)
__global__ void bm25_main(const int* __restrict__ ids, const int* __restrict__ mask,
                          const __hip_bfloat16* __restrict__ Wb,
                          float* __restrict__ out) {
    __shared__ int   stoks[SEQ];
    __shared__ float wts[SEQ];
    __shared__ int   nv;
    __shared__ float wred[3];

    int b = blockIdx.x;
    int tid = threadIdx.x;

    if (tid == 0) nv = 0;
    __syncthreads();

    // compact valid tokens (order irrelevant; sort follows)
    for (int i = tid; i < SEQ; i += NT) {
        int id = ids[(size_t)b * SEQ + i];
        int m  = mask[(size_t)b * SEQ + i];
        if (m == 1 && id > 100 && id < VOC) {
            stoks[atomicAdd(&nv, 1)] = id;
        }
    }
    __syncthreads();
    int n = nv;  // == doc_len (positions with multiplicity)

    // pad to 512 with +inf keys
    for (int i = n + tid; i < SEQ; i += NT) stoks[i] = 0x7fffffff;

    // bitonic sort of 512 ints (first barrier inside loop covers padding writes)
    for (int k = 2; k <= SEQ; k <<= 1) {
        for (int j = k >> 1; j > 0; j >>= 1) {
            __syncthreads();
            for (int i = tid; i < SEQ; i += NT) {
                int ixj = i ^ j;
                if (ixj > i) {
                    int a = stoks[i], c = stoks[ixj];
                    if ((a > c) == ((i & k) == 0)) { stoks[i] = c; stoks[ixj] = a; }
                }
            }
        }
    }
    __syncthreads();

    // per-position weight: score(tf)/tf = (K1+1)/(tf + K1*len_norm); tf via sorted runs
    float kln = K1 * fmaxf(1.0f + BPAR * ((float)n / 100.0f - 1.0f), 0.5f);
    for (int i = tid; i < n; i += NT) {
        int t = stoks[i];
        int lo = i; while (lo > 0 && stoks[lo - 1] == t) lo--;
        int hi = i; while (hi < n - 1 && stoks[hi + 1] == t) hi++;
        wts[i] = (K1 + 1.0f) / ((float)(hi - lo + 1) + kln);
    }
    __syncthreads();

    // gather-accumulate in ascending vocab order; thread owns bf16x4 chunk `tid`
    const ushort4* __restrict__ Wb4 = (const ushort4*)Wb;   // row stride DMODEL/4 = 192
    float4 acc = make_float4(0.f, 0.f, 0.f, 0.f);
    int p = 0;
    for (; p + PF <= n; p += PF) {
        ushort4 r[PF];
        float   w[PF];
#pragma unroll
        for (int q = 0; q < PF; q++) {
            r[q] = Wb4[(size_t)stoks[p + q] * (DMODEL / 4) + tid];
            w[q] = wts[p + q];
        }
#pragma unroll
        for (int q = 0; q < PF; q++) {
            acc.x = fmaf(w[q], b2f(r[q].x), acc.x);
            acc.y = fmaf(w[q], b2f(r[q].y), acc.y);
            acc.z = fmaf(w[q], b2f(r[q].z), acc.z);
            acc.w = fmaf(w[q], b2f(r[q].w), acc.w);
        }
    }
    for (; p < n; p++) {
        float w = wts[p];
        ushort4 r = Wb4[(size_t)stoks[p] * (DMODEL / 4) + tid];
        acc.x = fmaf(w, b2f(r.x), acc.x);
        acc.y = fmaf(w, b2f(r.y), acc.y);
        acc.z = fmaf(w, b2f(r.z), acc.z);
        acc.w = fmaf(w, b2f(r.w), acc.w);
    }

    // L2 norm over 768 dims (intermediate normalize cancels; 1e-10 term ~1e-10 rel)
    float ss = acc.x * acc.x + acc.y * acc.y + acc.z * acc.z + acc.w * acc.w;
#pragma unroll
    for (int off = 32; off > 0; off >>= 1) ss += __shfl_down(ss, off);
    if ((tid & 63) == 0) wred[tid >> 6] = ss;
    __syncthreads();
    float inv = rsqrtf(fmaxf(wred[0] + wred[1] + wred[2], 1e-30f));

    float4 o;
    o.x = acc.x * inv; o.y = acc.y * inv; o.z = acc.z * inv; o.w = acc.w * inv;
    ((float4*)(out + (size_t)b * DMODEL))[tid] = o;
}

extern "C" void kernel_launch(void* const* d_in, const int* in_sizes, int n_in,
                              void* d_out, int out_size, void* d_ws, size_t ws_size,
                              hipStream_t stream) {
    const int*   ids  = (const int*)d_in[0];
    const int*   mask = (const int*)d_in[1];
    const float* W    = (const float*)d_in[2];
    float* out = (float*)d_out;

    __hip_bfloat16* Wb = (__hip_bfloat16*)d_ws;            // 30000*768*2 = 46,080,000 B

    dim3 tgrid((VOC + 255) / 256, DMODEL / 64);
    dim3 tblock(64, 4);
    transpose_W256<<<tgrid, tblock, 0, stream>>>(W, Wb);

    bm25_main<<<B_ROWS, NT, 0, stream>>>(ids, mask, Wb, out);
}